// Round 12
// baseline (145.170 us; speedup 1.0000x reference)
//
#include <hip/hip_runtime.h>
#include <math.h>

#define N_STATES 32
#define N_TYPES 128
#define N_GENES 8192
#define N_SAMPLES 8192
#define N_TOT (N_SAMPLES * N_GENES)
#define LOG2PI_F 1.8378770664093453f

typedef float f32x2 __attribute__((ext_vector_type(2)));
typedef float f32x4 __attribute__((ext_vector_type(4)));
typedef unsigned int u32x2 __attribute__((ext_vector_type(2)));
typedef unsigned int u32x4 __attribute__((ext_vector_type(4)));

// round-to-nearest-even bf16 (upper 16 bits)
__device__ __forceinline__ unsigned int bf16r(float f) {
  unsigned int u = __builtin_bit_cast(unsigned int, f);
  return (u + 0x7FFFu + ((u >> 16) & 1u)) >> 16;
}

// logp from x and packed table entry (bf16 mu | bf16 inv)
__device__ __forceinline__ float logp_pk(float x, unsigned int tv) {
  float mu = __builtin_bit_cast(float, tv & 0xFFFF0000u);
  float iv = __builtin_bit_cast(float, tv << 16);
  float z = (x - mu) * iv;
  // logp = -0.5 z^2 - log(sigma) - 0.5 log(2pi);  log(sigma) = -log(inv)
  return fmaf(-0.5f * z, z, __logf(iv) - 0.5f * LOG2PI_F);
}

// ---------------- Kernel 1: packed per-(state,gene) table ----------------
// T[st,g] = bf16(mu)<<16 | bf16(1/sigma).  4 states/block, 512-gene chunks.
__global__ __launch_bounds__(256) void precompute_kernel(
    const float* __restrict__ cp, const float* __restrict__ Zmu,
    const float* __restrict__ Zs, unsigned int* __restrict__ T) {
  __shared__ float s_cp[4][N_TYPES], s_cp2[4][N_TYPES];
  const int st0 = blockIdx.y * 4;
  const int g0 = blockIdx.x * 512 + threadIdx.x * 2;

  for (int idx = threadIdx.x; idx < 4 * N_TYPES; idx += 256) {
    int s = idx >> 7, t = idx & (N_TYPES - 1);
    float c = cp[(st0 + s) * N_TYPES + t];
    s_cp[s][t] = c;
    s_cp2[s][t] = c * c;
  }
  __syncthreads();

  float mu[4][2] = {}, s2a[4][2] = {}, s13[4][2] = {};
#pragma unroll 1
  for (int t = 0; t < N_TYPES; t += 2) {
    f32x2 zm0 = *(const f32x2*)(Zmu + (size_t)t * N_GENES + g0);
    f32x2 zs0 = *(const f32x2*)(Zs  + (size_t)t * N_GENES + g0);
    f32x2 zm1 = *(const f32x2*)(Zmu + (size_t)(t + 1) * N_GENES + g0);
    f32x2 zs1 = *(const f32x2*)(Zs  + (size_t)(t + 1) * N_GENES + g0);
    f32x2 q0, q1;
#pragma unroll
    for (int j = 0; j < 2; ++j) {
      q0[j] = zs0[j] * (1.f - zs0[j]);
      q1[j] = zs1[j] * (1.f - zs1[j]);
    }
#pragma unroll
    for (int s = 0; s < 4; ++s) {
      float c0 = s_cp[s][t], c20 = s_cp2[s][t];
      float c1 = s_cp[s][t + 1], c21 = s_cp2[s][t + 1];
#pragma unroll
      for (int j = 0; j < 2; ++j) {
        mu[s][j]  = fmaf(c0, zm0[j], mu[s][j]);
        s2a[s][j] = fmaf(c0, zs0[j], s2a[s][j]);
        s13[s][j] = fmaf(c20, q0[j], s13[s][j]);
        mu[s][j]  = fmaf(c1, zm1[j], mu[s][j]);
        s2a[s][j] = fmaf(c1, zs1[j], s2a[s][j]);
        s13[s][j] = fmaf(c21, q1[j], s13[s][j]);
      }
    }
  }

#pragma unroll
  for (int s = 0; s < 4; ++s) {
    u32x2 pk;
#pragma unroll
    for (int j = 0; j < 2; ++j) {
      float sigma = s13[s][j] + s2a[s][j] * s2a[s][j];
      pk[j] = (bf16r(mu[s][j]) << 16) | bf16r(1.0f / sigma);
    }
    *(u32x2*)(T + (size_t)(st0 + s) * N_GENES + g0) = pk;
  }
}

// ---------------- Kernel 1b: deterministic counting sort of rows by state ---
// 1 block, 256 threads; thread t owns rows [32t, 32t+32). Stable, no atomics.
__global__ __launch_bounds__(256) void bucket_kernel(
    const int* __restrict__ day, int* __restrict__ rowlist,
    int* __restrict__ bstart, int* __restrict__ bcount) {
  __shared__ int cnt[256][N_STATES];   // 32 KB
  __shared__ int base[N_STATES];
  const int t = threadIdx.x;
  const int r0 = t * 32;

#pragma unroll
  for (int s = 0; s < N_STATES; ++s) cnt[t][s] = 0;
  __syncthreads();
  for (int k = 0; k < 32; ++k) cnt[t][day[r0 + k] - 1]++;
  __syncthreads();

  if (t < N_STATES) {                  // exclusive prefix over threads, per state
    int run = 0;
    for (int u = 0; u < 256; ++u) { int c = cnt[u][t]; cnt[u][t] = run; run += c; }
    base[t] = run;                     // bucket total (for now)
  }
  __syncthreads();
  if (t == 0) {                        // bucket bases
    int run = 0;
    for (int s = 0; s < N_STATES; ++s) {
      int tot = base[s];
      bstart[s] = run; bcount[s] = tot; base[s] = run; run += tot;
    }
  }
  __syncthreads();

  for (int k = 0; k < 32; ++k) {       // stable scatter
    int r = r0 + k, s = day[r] - 1;
    rowlist[base[s] + cnt[t][s]] = r;
    cnt[t][s]++;
  }
}

// ---------------- Kernel 2: main. block = (state, chunk, row-group) ----------
// Table slice (4 KB) staged ONCE in registers (u32x4/thread), then ~32 X-rows
// streamed against it: table traffic 256 MB -> 8 MB aggregate.
// Loads shifted -1 (clamped) -> ALIGNED NT f32x4 stores; out[r*NG + e] holds
// logp[r*NG + e - 1] (out[0] = scalar sum, written by reduce).
__global__ __launch_bounds__(256) void main_kernel(
    const float* __restrict__ X, const int* __restrict__ day,
    const unsigned int* __restrict__ T, const int* __restrict__ rowlist,
    const int* __restrict__ bstart, const int* __restrict__ bcount,
    float* __restrict__ out, float* __restrict__ partial) {
  const int b = blockIdx.x;
  const int s = b >> 6;                 // 32 states
  const int c = (b >> 3) & 7;           // 8 chunks of 1024 genes
  const int g = b & 7;                  // 8 row-groups (stride-8 over bucket)
  const int tid = threadIdx.x;
  const int g0 = c * 1024;
  const bool fix = (c == 0) && (tid == 0);

  // stage table slice, -1 shifted (clamped only for c==0,tid==0)
  int tix = s * N_GENES + g0 + 4 * tid - 1;
  if (fix) tix = s * N_GENES;
  u32x4 tb;
  __builtin_memcpy(&tb, T + tix, 16);

  const int cnt = bcount[s];
  const int* rl = rowlist + bstart[s];
  float acc = 0.f;

#pragma unroll 2
  for (int i = g; i < cnt; i += 8) {
    const int r = rl[i];
    // special-case inputs (chunk0/thread0): issue early, overlap with xb load
    float pmx = 0.f; unsigned int pmt = 0;
    if (fix && r > 0) {
      int stP = day[r - 1] - 1;
      pmx = X[(size_t)r * N_GENES - 1];
      pmt = T[(size_t)stP * N_GENES + N_GENES - 1];
    }
    const float* Xp = X + (size_t)r * N_GENES + g0 + 4 * tid - 1;
    if (fix) Xp = X + (size_t)r * N_GENES;
    f32x4 xb;
    __builtin_memcpy(&xb, Xp, 16);

    f32x4 p;
#pragma unroll
    for (int j = 0; j < 4; ++j) p[j] = logp_pk(xb[j], tb[j]);
    if (fix) {
      // clamped loads gave elements 0..3: shift lanes, insert prev-row element
      p[3] = p[2]; p[2] = p[1]; p[1] = p[0];
      p[0] = (r > 0) ? logp_pk(pmx, pmt) : 0.f;   // row 0: junk, reduce fixes
    }
    __builtin_nontemporal_store(p, (f32x4*)(out + (size_t)r * N_GENES + g0 + 4 * tid));
    acc += (p[0] + p[1]) + (p[2] + p[3]);
  }

  // last logp element (N_TOT-1) is outside every shifted window
  if (b == 0 && tid == 0) {
    int sl = day[N_SAMPLES - 1] - 1;
    float p = logp_pk(X[(size_t)N_TOT - 1],
                      T[(size_t)sl * N_GENES + N_GENES - 1]);
    out[N_TOT] = p;
    acc += p;
  }

#pragma unroll
  for (int off = 32; off; off >>= 1) acc += __shfl_down(acc, off, 64);
  __shared__ float s_w[4];
  int lane = tid & 63, w = tid >> 6;
  if (lane == 0) s_w[w] = acc;
  __syncthreads();
  if (tid == 0)
    partial[blockIdx.x] = (s_w[0] + s_w[1]) + (s_w[2] + s_w[3]);
}

// ---------------- Kernel 3: final reduction (deterministic, double) ----------------
__global__ __launch_bounds__(1024) void reduce_kernel(
    const float* __restrict__ partial, int n, float* __restrict__ out0) {
  double acc = 0.0;
  for (int i = threadIdx.x; i < n; i += 1024) acc += (double)partial[i];
#pragma unroll
  for (int off = 32; off; off >>= 1) acc += __shfl_down(acc, off, 64);
  __shared__ double s_w[16];
  int lane = threadIdx.x & 63, w = threadIdx.x >> 6;
  if (lane == 0) s_w[w] = acc;
  __syncthreads();
  if (threadIdx.x == 0) {
    double s = 0.0;
#pragma unroll
    for (int i = 0; i < 16; ++i) s += s_w[i];
    out0[0] = (float)s;
  }
}

extern "C" void kernel_launch(void* const* d_in, const int* in_sizes, int n_in,
                              void* d_out, int out_size, void* d_ws, size_t ws_size,
                              hipStream_t stream) {
  const float* cp  = (const float*)d_in[0];   // (32,128)
  const float* Zmu = (const float*)d_in[1];   // (128,8192)
  const float* Zs  = (const float*)d_in[2];   // (128,8192)
  const float* X   = (const float*)d_in[3];   // (8192,8192)
  const int*   day = (const int*)d_in[4];     // (8192,)
  float* out = (float*)d_out;                 // [0]=sum, [1..]=logp flat
  float* ws  = (float*)d_ws;

  const int TBL = N_STATES * N_GENES;         // 262144
  unsigned int* T = (unsigned int*)ws;        // 1 MB packed table
  int* rowlist = (int*)(ws + TBL);            // 8192
  int* bstart  = rowlist + N_SAMPLES;         // 32
  int* bcount  = bstart + N_STATES;           // 32
  float* partial = (float*)(bcount + N_STATES);  // 2048

  dim3 g1(N_GENES / 512, N_STATES / 4);       // 16 x 8 = 128 blocks
  precompute_kernel<<<g1, 256, 0, stream>>>(cp, Zmu, Zs, T);
  bucket_kernel<<<1, 256, 0, stream>>>(day, rowlist, bstart, bcount);

  const int NBLK = N_STATES * 8 * 8;          // 2048 blocks
  main_kernel<<<NBLK, 256, 0, stream>>>(X, day, T, rowlist, bstart, bcount,
                                        out, partial);
  reduce_kernel<<<1, 1024, 0, stream>>>(partial, NBLK, out);
}